// Round 3
// baseline (240.907 us; speedup 1.0000x reference)
//
#include <hip/hip_runtime.h>
#include <math.h>

// Fused ConvTranspose2d(64->64,k4,s2,p1) + MaxPool2x2 + Hardtanh + mean + tanh
// via bf16 MFMA implicit GEMM. Quad/tap decomposition verified exact (round 1).
//
// MFMA 16x16x32 bf16: A lane l: row=l&15, k=(l>>4)*8+j ; B same with col;
//                     C lane l: col=l&15, row=(l>>4)*4+j   [HW-verified m89]

typedef __attribute__((ext_vector_type(8))) short short8;
typedef __attribute__((ext_vector_type(4))) float f32x4;

#define XS_ROW 66
#define XS_CI 72          // halfwords per (row,iw) slot: 64 ci + 8 pad
#define XS_CI_U32 36

__device__ __forceinline__ unsigned short f2bf(float f) {
    unsigned int u = __builtin_bit_cast(unsigned int, f);
    u += 0x7fffu + ((u >> 16) & 1u);   // round-to-nearest-even
    return (unsigned short)(u >> 16);
}

// ---------------------------------------------------------------------------
// Weight prep (coalesced): read w[ci][co][16] as float4 (1KB contiguous per
// wave), scatter bf16 into B-fragment layout:
//   hw idx = (((qt*4 + n)*2 + kb2)*64 + lane)*8 + j
//   ci = kb2*32 + (lane>>4)*8 + j, co = n*16 + (lane&15), (kh,kw) = f(qt).
// Also zeroes partial[2048] and the ticket counter.
// ---------------------------------------------------------------------------
__global__ void wprep_kernel(const float* __restrict__ w,
                             unsigned short* __restrict__ wsB,
                             float* __restrict__ partial,
                             unsigned int* __restrict__ counter)
{
    const int g = blockIdx.x * 256 + threadIdx.x;   // 0..16383
    const int ci  = g >> 8;
    const int co  = (g >> 2) & 63;
    const int kkq = g & 3;

    const float4 v = *(const float4*)(w + (size_t)ci * 1024 + (size_t)co * 16 + kkq * 4);
    const float vv[4] = {v.x, v.y, v.z, v.w};

    const int n    = co >> 4;
    const int kb2  = ci >> 5;
    const int lane = ((ci >> 3) & 3) * 16 + (co & 15);
    const int j    = ci & 7;

    // inverse of the forward (q,t)->(kh,kw) map (verified against fwd table)
    constexpr int H2Q[4] = {1, 0, 1, 0};
    constexpr int H2T[4] = {1, 0, 0, 1};

    #pragma unroll
    for (int j4 = 0; j4 < 4; ++j4) {
        const int kk = kkq * 4 + j4;
        const int kh = kk >> 2, kw = kk & 3;
        const int q  = H2Q[kh] * 2 + H2Q[kw];
        const int t  = H2T[kh] * 2 + H2T[kw];
        const int qt = q * 4 + t;
        const size_t idx = ((((size_t)(qt * 4 + n)) * 2 + kb2) * 64 + lane) * 8 + j;
        wsB[idx] = f2bf(vv[j4]);
    }
    if (g < 2048) partial[g] = 0.f;
    if (g == 0)   *counter = 0u;
}

// ---------------------------------------------------------------------------
// Main kernel: 1024 blocks x 256 threads (4 waves).
// Block = (batch b, pooled-row-pair rp), XCD-swizzled for halo L2 locality.
// Wave wv: r = wv>>1 (pooled row ph0+r), ch = wv&1 (co half).
// Per wave: m=4 px tiles (64 px = full row), n=2 co tiles (32 co).
// Last block (atomic ticket) performs the tanh(mean) finalize.
// ---------------------------------------------------------------------------
__global__ __launch_bounds__(256, 4) void convt_mfma_kernel(
    const float* __restrict__ x,           // [32][64][64][64]
    const float* __restrict__ bias,        // [64]
    const unsigned short* __restrict__ wsB,
    float* __restrict__ partial,           // [2048]
    unsigned int* __restrict__ counter,
    float* __restrict__ out)               // [2048]
{
    __shared__ __align__(16) unsigned int xs[4 * XS_ROW * XS_CI_U32];  // 38016 B
    __shared__ unsigned int lastflag;

    const int wg  = blockIdx.x;       // 0..1023
    const int xcd = wg & 7;
    const int k   = wg >> 3;          // 0..127
    const int b   = xcd * 4 + (k >> 5);
    const int rp  = k & 31;
    const int ph0 = rp * 2;
    const int tid = threadIdx.x;

    // ---- stage x tile: input rows ph0-1..ph0+2, iw -1..64, 64 ci (bf16) ----
    {
        const int iw   = tid & 63;
        const int part = tid >> 6;    // ci block of 16
        #pragma unroll
        for (int r4 = 0; r4 < 4; ++r4) {
            const int  ih    = ph0 - 1 + r4;
            const bool rowok = ((unsigned)ih < 64u);
            unsigned int pk[8];
            #pragma unroll
            for (int h = 0; h < 8; ++h) {
                const int ci = part * 16 + h * 2;
                float v0 = 0.f, v1 = 0.f;
                if (rowok) {
                    const size_t base = (((size_t)(b * 64 + ci)) * 64 + ih) * 64 + iw;
                    v0 = x[base];
                    v1 = x[base + 4096];
                }
                pk[h] = (unsigned)f2bf(v0) | ((unsigned)f2bf(v1) << 16);
            }
            unsigned int* dst = &xs[(r4 * XS_ROW + iw + 1) * XS_CI_U32 + part * 8];
            *(uint4*)(dst)     = make_uint4(pk[0], pk[1], pk[2], pk[3]);
            *(uint4*)(dst + 4) = make_uint4(pk[4], pk[5], pk[6], pk[7]);
            if (iw == 0 || iw == 63) {
                const int slot = (iw == 0) ? 0 : 65;
                unsigned int* zp = &xs[(r4 * XS_ROW + slot) * XS_CI_U32 + part * 8];
                *(uint4*)(zp)     = make_uint4(0u, 0u, 0u, 0u);
                *(uint4*)(zp + 4) = make_uint4(0u, 0u, 0u, 0u);
            }
        }
    }
    __syncthreads();

    const int wv   = tid >> 6;
    const int r    = wv >> 1;         // pooled row within pair
    const int ch   = wv & 1;          // co half
    const int lane = tid & 63;
    const int p    = lane & 15;
    const int hi   = lane >> 4;

    const unsigned short* xs16 = (const unsigned short*)xs;
    const int abase = ((r + 1) * XS_ROW + (p + 1)) * XS_CI + hi * 8;
    const unsigned short* wB = wsB + (size_t)lane * 8;

    constexpr int DHt[16] = {0,0,-1,-1, 0,0,-1,-1, 0,0,1,1, 0,0,1,1};
    constexpr int DWt[16] = {0,-1,0,-1, 0,1,0,1, 0,-1,0,-1, 0,1,0,1};

    f32x4 vmax[4][2];
    f32x4 acc[4][2];

    #pragma unroll
    for (int q = 0; q < 4; ++q) {
        #pragma unroll
        for (int m = 0; m < 4; ++m)
            #pragma unroll
            for (int nn = 0; nn < 2; ++nn)
                acc[m][nn] = (f32x4){0.f, 0.f, 0.f, 0.f};

        #pragma unroll
        for (int t = 0; t < 4; ++t) {
            const int qt = q * 4 + t;
            const int dh = DHt[qt], dw = DWt[qt];
            #pragma unroll
            for (int kb2 = 0; kb2 < 2; ++kb2) {
                short8 Bf[2];
                #pragma unroll
                for (int nn = 0; nn < 2; ++nn)
                    Bf[nn] = *(const short8*)(
                        wB + (((size_t)(qt * 4 + (ch * 2 + nn)) * 2 + kb2) << 9));

                short8 Af[4];
                const int ao = abase + dh * (XS_ROW * XS_CI) + dw * XS_CI + kb2 * 32;
                #pragma unroll
                for (int m = 0; m < 4; ++m)
                    Af[m] = *(const short8*)(xs16 + ao + m * (16 * XS_CI));

                #pragma unroll
                for (int m = 0; m < 4; ++m)
                    #pragma unroll
                    for (int nn = 0; nn < 2; ++nn)
                        acc[m][nn] = __builtin_amdgcn_mfma_f32_16x16x32_bf16(
                            Af[m], Bf[nn], acc[m][nn], 0, 0, 0);
            }
        }

        if (q == 0) {
            #pragma unroll
            for (int m = 0; m < 4; ++m)
                #pragma unroll
                for (int nn = 0; nn < 2; ++nn)
                    vmax[m][nn] = acc[m][nn];
        } else {
            #pragma unroll
            for (int m = 0; m < 4; ++m)
                #pragma unroll
                for (int nn = 0; nn < 2; ++nn)
                    #pragma unroll
                    for (int j = 0; j < 4; ++j)
                        vmax[m][nn][j] = fmaxf(vmax[m][nn][j], acc[m][nn][j]);
        }
    }

    // ---- epilogue: bias + hardtanh + sum over this wave's 64 px ----
    #pragma unroll
    for (int nn = 0; nn < 2; ++nn) {
        const int co = ch * 32 + nn * 16 + p;
        const float bv = bias[co];
        float s = 0.f;
        #pragma unroll
        for (int m = 0; m < 4; ++m)
            #pragma unroll
            for (int j = 0; j < 4; ++j) {
                float v = vmax[m][nn][j] + bv;
                v = fminf(fmaxf(v, -1.f), 1.f);
                s += v;
            }
        s += __shfl_xor(s, 16, 64);
        s += __shfl_xor(s, 32, 64);
        if (hi == 0) atomicAdd(&partial[b * 64 + co], s);
    }

    // ---- last-block finalize via device-scope ticket ----
    __threadfence();
    __syncthreads();
    if (tid == 0) lastflag = atomicAdd(counter, 1u);
    __syncthreads();
    if (lastflag == 1023u) {
        __threadfence();
        for (int i = tid; i < 2048; i += 256) {
            const float v = __hip_atomic_load(&partial[i], __ATOMIC_RELAXED,
                                              __HIP_MEMORY_SCOPE_AGENT);
            out[i] = tanhf(v * (1.0f / 4096.0f));
        }
    }
}

extern "C" void kernel_launch(void* const* d_in, const int* in_sizes, int n_in,
                              void* d_out, int out_size, void* d_ws, size_t ws_size,
                              hipStream_t stream)
{
    (void)in_sizes; (void)n_in; (void)out_size; (void)ws_size;
    const float* x  = (const float*)d_in[0];
    const float* w  = (const float*)d_in[1];
    const float* bi = (const float*)d_in[2];
    float* out = (float*)d_out;

    unsigned short* wsB     = (unsigned short*)d_ws;                        // 131072 B
    float*          partial = (float*)((char*)d_ws + 131072);               // 8192 B
    unsigned int*   counter = (unsigned int*)((char*)d_ws + 131072 + 8192); // 4 B

    wprep_kernel<<<64, 256, 0, stream>>>(w, wsB, partial, counter);
    convt_mfma_kernel<<<1024, 256, 0, stream>>>(x, bi, wsB, partial, counter, out);
}

// Round 4
// 220.395 us; speedup vs baseline: 1.0931x; 1.0931x over previous
//
#include <hip/hip_runtime.h>
#include <math.h>

// Fused ConvTranspose2d(64->64,k4,s2,p1) + MaxPool2x2 + Hardtanh + mean + tanh
// via bf16 MFMA implicit GEMM. Quad/tap decomposition verified exact (round 1,
// absmax 0.0 fp32; bf16 path absmax 0.0039, rounds 2-3).
//
// MFMA 16x16x32 bf16: A lane l: row=l&15, k=(l>>4)*8+j ; B same with col;
//                     C lane l: col=l&15, row=(l>>4)*4+j   [HW-verified m89]
//
// Round-4 change: anti-spill. 8 waves/block, each wave = (pooled row, 16-co
// quarter) -> accumulator state 32 VGPR/wave (acc[4]+vmax[4] f32x4). Round 2/3
// spilled (WRITE_SIZE 46/148 MB) because 64-128 f32 of live accumulators
// exceeded the launch_bounds-derived register budget (~256/min_waves_per_eu).

typedef __attribute__((ext_vector_type(8))) short short8;
typedef __attribute__((ext_vector_type(4))) float f32x4;

#define XS_ROW 66
#define XS_CI 72          // halfwords per (row,iw) slot: 64 ci + 8 pad
#define XS_CI_U32 36

__device__ __forceinline__ unsigned short f2bf(float f) {
    unsigned int u = __builtin_bit_cast(unsigned int, f);
    u += 0x7fffu + ((u >> 16) & 1u);   // round-to-nearest-even
    return (unsigned short)(u >> 16);
}

// ---------------------------------------------------------------------------
// Weight prep (coalesced): read w[ci][co][16] as float4, scatter bf16 into
// B-fragment layout: hw idx = (((qt*4 + n)*2 + kb2)*64 + lane)*8 + j
//   ci = kb2*32 + (lane>>4)*8 + j, co = n*16 + (lane&15), (kh,kw) = f(qt).
// Also zeroes partial[2048] and the ticket counter.
// ---------------------------------------------------------------------------
__global__ void wprep_kernel(const float* __restrict__ w,
                             unsigned short* __restrict__ wsB,
                             float* __restrict__ partial,
                             unsigned int* __restrict__ counter)
{
    const int g = blockIdx.x * 256 + threadIdx.x;   // 0..16383
    const int ci  = g >> 8;
    const int co  = (g >> 2) & 63;
    const int kkq = g & 3;

    const float4 v = *(const float4*)(w + (size_t)ci * 1024 + (size_t)co * 16 + kkq * 4);
    const float vv[4] = {v.x, v.y, v.z, v.w};

    const int n    = co >> 4;
    const int kb2  = ci >> 5;
    const int lane = ((ci >> 3) & 3) * 16 + (co & 15);
    const int j    = ci & 7;

    // inverse of the forward (q,t)->(kh,kw) map
    constexpr int H2Q[4] = {1, 0, 1, 0};
    constexpr int H2T[4] = {1, 0, 0, 1};

    #pragma unroll
    for (int j4 = 0; j4 < 4; ++j4) {
        const int kk = kkq * 4 + j4;
        const int kh = kk >> 2, kw = kk & 3;
        const int q  = H2Q[kh] * 2 + H2Q[kw];
        const int t  = H2T[kh] * 2 + H2T[kw];
        const int qt = q * 4 + t;
        const size_t idx = ((((size_t)(qt * 4 + n)) * 2 + kb2) * 64 + lane) * 8 + j;
        wsB[idx] = f2bf(vv[j4]);
    }
    if (g < 2048) partial[g] = 0.f;
    if (g == 0)   *counter = 0u;
}

// ---------------------------------------------------------------------------
// Main kernel: 1024 blocks x 512 threads (8 waves).
// Block = (batch b, pooled-row-pair rp), XCD-contiguous block map.
// Wave wv: r = wv>>2 (pooled row ph0+r), ch = wv&3 (16-co quarter).
// Per wave: m = 4 px tiles (full 64-px row) x 1 co tile of 16.
// Last block (atomic ticket) performs the tanh(mean) finalize.
// ---------------------------------------------------------------------------
__global__ __launch_bounds__(512, 2) void convt_mfma_kernel(
    const float* __restrict__ x,           // [32][64][64][64]
    const float* __restrict__ bias,        // [64]
    const unsigned short* __restrict__ wsB,
    float* __restrict__ partial,           // [2048]
    unsigned int* __restrict__ counter,
    float* __restrict__ out)               // [2048]
{
    __shared__ __align__(16) unsigned int xs[4 * XS_ROW * XS_CI_U32];  // 38016 B
    __shared__ unsigned int lastflag;

    const int wg  = blockIdx.x;       // 0..1023
    const int xcd = wg & 7;
    const int k   = wg >> 3;          // 0..127
    const int b   = xcd * 4 + (k >> 5);
    const int rp  = k & 31;
    const int ph0 = rp * 2;
    const int tid = threadIdx.x;

    // ---- stage x tile: input rows ph0-1..ph0+2, iw -1..64, 64 ci (bf16) ----
    {
        const int iw   = tid & 63;
        const int part = tid >> 6;    // 0..7 : ci block of 8
        #pragma unroll
        for (int r4 = 0; r4 < 4; ++r4) {
            const int  ih    = ph0 - 1 + r4;
            const bool rowok = ((unsigned)ih < 64u);
            unsigned int pk[4];
            #pragma unroll
            for (int h = 0; h < 4; ++h) {
                const int ci = part * 8 + h * 2;
                float v0 = 0.f, v1 = 0.f;
                if (rowok) {
                    const size_t base = (((size_t)(b * 64 + ci)) * 64 + ih) * 64 + iw;
                    v0 = x[base];
                    v1 = x[base + 4096];
                }
                pk[h] = (unsigned)f2bf(v0) | ((unsigned)f2bf(v1) << 16);
            }
            unsigned int* dst = &xs[(r4 * XS_ROW + iw + 1) * XS_CI_U32 + part * 4];
            *(uint4*)(dst) = make_uint4(pk[0], pk[1], pk[2], pk[3]);
            if (iw == 0 || iw == 63) {
                const int slot = (iw == 0) ? 0 : 65;
                unsigned int* zp = &xs[(r4 * XS_ROW + slot) * XS_CI_U32 + part * 4];
                *(uint4*)(zp) = make_uint4(0u, 0u, 0u, 0u);
            }
        }
    }
    __syncthreads();

    const int wv   = tid >> 6;        // 0..7
    const int r    = wv >> 2;         // pooled row within pair
    const int ch   = wv & 3;          // co quarter (16 co)
    const int lane = tid & 63;
    const int p    = lane & 15;
    const int hi   = lane >> 4;

    const unsigned short* xs16 = (const unsigned short*)xs;
    const int abase = ((r + 1) * XS_ROW + (p + 1)) * XS_CI + hi * 8;
    const unsigned short* wB = wsB + (size_t)lane * 8;

    constexpr int DHt[16] = {0,0,-1,-1, 0,0,-1,-1, 0,0,1,1, 0,0,1,1};
    constexpr int DWt[16] = {0,-1,0,-1, 0,1,0,1, 0,-1,0,-1, 0,1,0,1};

    f32x4 vmax[4];
    f32x4 acc[4];

    #pragma unroll
    for (int q = 0; q < 4; ++q) {
        #pragma unroll
        for (int m = 0; m < 4; ++m)
            acc[m] = (f32x4){0.f, 0.f, 0.f, 0.f};

        #pragma unroll
        for (int t = 0; t < 4; ++t) {
            const int qt = q * 4 + t;
            const int dh = DHt[qt], dw = DWt[qt];
            #pragma unroll
            for (int kb2 = 0; kb2 < 2; ++kb2) {
                const short8 Bf = *(const short8*)(
                    wB + (((size_t)(qt * 4 + ch) * 2 + kb2) << 9));

                short8 Af[4];
                const int ao = abase + dh * (XS_ROW * XS_CI) + dw * XS_CI + kb2 * 32;
                #pragma unroll
                for (int m = 0; m < 4; ++m)
                    Af[m] = *(const short8*)(xs16 + ao + m * (16 * XS_CI));

                #pragma unroll
                for (int m = 0; m < 4; ++m)
                    acc[m] = __builtin_amdgcn_mfma_f32_16x16x32_bf16(
                        Af[m], Bf, acc[m], 0, 0, 0);
            }
        }

        if (q == 0) {
            #pragma unroll
            for (int m = 0; m < 4; ++m)
                vmax[m] = acc[m];
        } else {
            #pragma unroll
            for (int m = 0; m < 4; ++m)
                #pragma unroll
                for (int j = 0; j < 4; ++j)
                    vmax[m][j] = fmaxf(vmax[m][j], acc[m][j]);
        }
    }

    // ---- epilogue: bias + hardtanh + sum over this wave's 64 px ----
    {
        const int co = ch * 16 + p;
        const float bv = bias[co];
        float s = 0.f;
        #pragma unroll
        for (int m = 0; m < 4; ++m)
            #pragma unroll
            for (int j = 0; j < 4; ++j) {
                float v = vmax[m][j] + bv;
                v = fminf(fmaxf(v, -1.f), 1.f);
                s += v;
            }
        s += __shfl_xor(s, 16, 64);
        s += __shfl_xor(s, 32, 64);
        if (hi == 0) atomicAdd(&partial[b * 64 + co], s);
    }

    // ---- last-block finalize via device-scope ticket ----
    __threadfence();
    __syncthreads();
    if (tid == 0) lastflag = atomicAdd(counter, 1u);
    __syncthreads();
    if (lastflag == 1023u) {
        __threadfence();
        for (int i = tid; i < 2048; i += 512) {
            const float v = __hip_atomic_load(&partial[i], __ATOMIC_RELAXED,
                                              __HIP_MEMORY_SCOPE_AGENT);
            out[i] = tanhf(v * (1.0f / 4096.0f));
        }
    }
}

extern "C" void kernel_launch(void* const* d_in, const int* in_sizes, int n_in,
                              void* d_out, int out_size, void* d_ws, size_t ws_size,
                              hipStream_t stream)
{
    (void)in_sizes; (void)n_in; (void)out_size; (void)ws_size;
    const float* x  = (const float*)d_in[0];
    const float* w  = (const float*)d_in[1];
    const float* bi = (const float*)d_in[2];
    float* out = (float*)d_out;

    unsigned short* wsB     = (unsigned short*)d_ws;                        // 131072 B
    float*          partial = (float*)((char*)d_ws + 131072);               // 8192 B
    unsigned int*   counter = (unsigned int*)((char*)d_ws + 131072 + 8192); // 4 B

    wprep_kernel<<<64, 256, 0, stream>>>(w, wsB, partial, counter);
    convt_mfma_kernel<<<1024, 512, 0, stream>>>(x, bi, wsB, partial, counter, out);
}

// Round 5
// 102.050 us; speedup vs baseline: 2.3607x; 2.1597x over previous
//
#include <hip/hip_runtime.h>
#include <math.h>

// Fused ConvTranspose2d(64->64,k4,s2,p1) + MaxPool2x2 + Hardtanh + mean + tanh
// via bf16 MFMA implicit GEMM. Quad/tap decomposition verified exact (round 1,
// absmax 0.0 fp32; bf16 path absmax 0.0039, rounds 2-4).
//
// MFMA 16x16x32 bf16: A lane l: row=l&15, k=(l>>4)*8+j ; B same with col;
//                     C lane l: col=l&15, row=(l>>4)*4+j   [HW-verified m89]
//
// Round-5 change: REMOVED the in-kernel ticket finalize. Round 3/4's
// __threadfence() (agent-scope fence -> L2 writeback on 8 non-coherent XCD
// L2s, once per block x 1024 blocks) serialized ~100+ us with all pipes idle
// (MfmaUtil 4%, VALUBusy 4%, HBM 1.3%). Separate finalize kernel instead;
// inter-dispatch ordering provides visibility with ONE flush total.

typedef __attribute__((ext_vector_type(8))) short short8;
typedef __attribute__((ext_vector_type(4))) float f32x4;

#define XS_ROW 66
#define XS_CI 72          // halfwords per (row,iw) slot: 64 ci + 8 pad
#define XS_CI_U32 36

__device__ __forceinline__ unsigned short f2bf(float f) {
    unsigned int u = __builtin_bit_cast(unsigned int, f);
    u += 0x7fffu + ((u >> 16) & 1u);   // round-to-nearest-even
    return (unsigned short)(u >> 16);
}

// ---------------------------------------------------------------------------
// Weight prep (coalesced): read w[ci][co][16] as float4, scatter bf16 into
// B-fragment layout: hw idx = (((qt*4 + n)*2 + kb2)*64 + lane)*8 + j
//   ci = kb2*32 + (lane>>4)*8 + j, co = n*16 + (lane&15), (kh,kw) = f(qt).
// Also zeroes partial[2048].
// ---------------------------------------------------------------------------
__global__ void wprep_kernel(const float* __restrict__ w,
                             unsigned short* __restrict__ wsB,
                             float* __restrict__ partial)
{
    const int g = blockIdx.x * 256 + threadIdx.x;   // 0..16383
    const int ci  = g >> 8;
    const int co  = (g >> 2) & 63;
    const int kkq = g & 3;

    const float4 v = *(const float4*)(w + (size_t)ci * 1024 + (size_t)co * 16 + kkq * 4);
    const float vv[4] = {v.x, v.y, v.z, v.w};

    const int n    = co >> 4;
    const int kb2  = ci >> 5;
    const int lane = ((ci >> 3) & 3) * 16 + (co & 15);
    const int j    = ci & 7;

    // inverse of the forward (q,t)->(kh,kw) map
    constexpr int H2Q[4] = {1, 0, 1, 0};
    constexpr int H2T[4] = {1, 0, 0, 1};

    #pragma unroll
    for (int j4 = 0; j4 < 4; ++j4) {
        const int kk = kkq * 4 + j4;
        const int kh = kk >> 2, kw = kk & 3;
        const int q  = H2Q[kh] * 2 + H2Q[kw];
        const int t  = H2T[kh] * 2 + H2T[kw];
        const int qt = q * 4 + t;
        const size_t idx = ((((size_t)(qt * 4 + n)) * 2 + kb2) * 64 + lane) * 8 + j;
        wsB[idx] = f2bf(vv[j4]);
    }
    if (g < 2048) partial[g] = 0.f;
}

// ---------------------------------------------------------------------------
// Main kernel: 1024 blocks x 512 threads (8 waves).
// Block = (batch b, pooled-row-pair rp), XCD-contiguous block map.
// Wave wv: r = wv>>2 (pooled row ph0+r), ch = wv&3 (16-co quarter).
// Per wave: m = 4 px tiles (full 64-px row) x 1 co tile of 16.
// ---------------------------------------------------------------------------
__global__ __launch_bounds__(512, 2) void convt_mfma_kernel(
    const float* __restrict__ x,           // [32][64][64][64]
    const float* __restrict__ bias,        // [64]
    const unsigned short* __restrict__ wsB,
    float* __restrict__ partial)           // [2048]
{
    __shared__ __align__(16) unsigned int xs[4 * XS_ROW * XS_CI_U32];  // 38016 B

    const int wg  = blockIdx.x;       // 0..1023
    const int xcd = wg & 7;
    const int k   = wg >> 3;          // 0..127
    const int b   = xcd * 4 + (k >> 5);
    const int rp  = k & 31;
    const int ph0 = rp * 2;
    const int tid = threadIdx.x;

    // ---- stage x tile: input rows ph0-1..ph0+2, iw -1..64, 64 ci (bf16) ----
    {
        const int iw   = tid & 63;
        const int part = tid >> 6;    // 0..7 : ci block of 8
        #pragma unroll
        for (int r4 = 0; r4 < 4; ++r4) {
            const int  ih    = ph0 - 1 + r4;
            const bool rowok = ((unsigned)ih < 64u);
            unsigned int pk[4];
            #pragma unroll
            for (int h = 0; h < 4; ++h) {
                const int ci = part * 8 + h * 2;
                float v0 = 0.f, v1 = 0.f;
                if (rowok) {
                    const size_t base = (((size_t)(b * 64 + ci)) * 64 + ih) * 64 + iw;
                    v0 = x[base];
                    v1 = x[base + 4096];
                }
                pk[h] = (unsigned)f2bf(v0) | ((unsigned)f2bf(v1) << 16);
            }
            unsigned int* dst = &xs[(r4 * XS_ROW + iw + 1) * XS_CI_U32 + part * 4];
            *(uint4*)(dst) = make_uint4(pk[0], pk[1], pk[2], pk[3]);
            if (iw == 0 || iw == 63) {
                const int slot = (iw == 0) ? 0 : 65;
                unsigned int* zp = &xs[(r4 * XS_ROW + slot) * XS_CI_U32 + part * 4];
                *(uint4*)(zp) = make_uint4(0u, 0u, 0u, 0u);
            }
        }
    }
    __syncthreads();

    const int wv   = tid >> 6;        // 0..7
    const int r    = wv >> 2;         // pooled row within pair
    const int ch   = wv & 3;          // co quarter (16 co)
    const int lane = tid & 63;
    const int p    = lane & 15;
    const int hi   = lane >> 4;

    const unsigned short* xs16 = (const unsigned short*)xs;
    const int abase = ((r + 1) * XS_ROW + (p + 1)) * XS_CI + hi * 8;
    const unsigned short* wB = wsB + (size_t)lane * 8;

    constexpr int DHt[16] = {0,0,-1,-1, 0,0,-1,-1, 0,0,1,1, 0,0,1,1};
    constexpr int DWt[16] = {0,-1,0,-1, 0,1,0,1, 0,-1,0,-1, 0,1,0,1};

    f32x4 vmax[4];
    f32x4 acc[4];

    #pragma unroll
    for (int q = 0; q < 4; ++q) {
        #pragma unroll
        for (int m = 0; m < 4; ++m)
            acc[m] = (f32x4){0.f, 0.f, 0.f, 0.f};

        #pragma unroll
        for (int t = 0; t < 4; ++t) {
            const int qt = q * 4 + t;
            const int dh = DHt[qt], dw = DWt[qt];
            #pragma unroll
            for (int kb2 = 0; kb2 < 2; ++kb2) {
                const short8 Bf = *(const short8*)(
                    wB + (((size_t)(qt * 4 + ch) * 2 + kb2) << 9));

                short8 Af[4];
                const int ao = abase + dh * (XS_ROW * XS_CI) + dw * XS_CI + kb2 * 32;
                #pragma unroll
                for (int m = 0; m < 4; ++m)
                    Af[m] = *(const short8*)(xs16 + ao + m * (16 * XS_CI));

                #pragma unroll
                for (int m = 0; m < 4; ++m)
                    acc[m] = __builtin_amdgcn_mfma_f32_16x16x32_bf16(
                        Af[m], Bf, acc[m], 0, 0, 0);
            }
        }

        if (q == 0) {
            #pragma unroll
            for (int m = 0; m < 4; ++m)
                vmax[m] = acc[m];
        } else {
            #pragma unroll
            for (int m = 0; m < 4; ++m)
                #pragma unroll
                for (int j = 0; j < 4; ++j)
                    vmax[m][j] = fmaxf(vmax[m][j], acc[m][j]);
        }
    }

    // ---- epilogue: bias + hardtanh + sum over this wave's 64 px ----
    {
        const int co = ch * 16 + p;
        const float bv = bias[co];
        float s = 0.f;
        #pragma unroll
        for (int m = 0; m < 4; ++m)
            #pragma unroll
            for (int j = 0; j < 4; ++j) {
                float v = vmax[m][j] + bv;
                v = fminf(fmaxf(v, -1.f), 1.f);
                s += v;
            }
        s += __shfl_xor(s, 16, 64);
        s += __shfl_xor(s, 32, 64);
        if (hi == 0) atomicAdd(&partial[b * 64 + co], s);
    }
}

__global__ void finalize_kernel(const float* __restrict__ partial, float* __restrict__ out)
{
    const int i = blockIdx.x * blockDim.x + threadIdx.x;
    if (i < 2048) out[i] = tanhf(partial[i] * (1.0f / 4096.0f));
}

extern "C" void kernel_launch(void* const* d_in, const int* in_sizes, int n_in,
                              void* d_out, int out_size, void* d_ws, size_t ws_size,
                              hipStream_t stream)
{
    (void)in_sizes; (void)n_in; (void)out_size; (void)ws_size;
    const float* x  = (const float*)d_in[0];
    const float* w  = (const float*)d_in[1];
    const float* bi = (const float*)d_in[2];
    float* out = (float*)d_out;

    unsigned short* wsB     = (unsigned short*)d_ws;           // 131072 B
    float*          partial = (float*)((char*)d_ws + 131072);  // 8192 B

    wprep_kernel<<<64, 256, 0, stream>>>(w, wsB, partial);
    convt_mfma_kernel<<<1024, 512, 0, stream>>>(x, bi, wsB, partial);
    finalize_kernel<<<8, 256, 0, stream>>>(partial, out);
}

// Round 6
// 98.431 us; speedup vs baseline: 2.4475x; 1.0368x over previous
//
#include <hip/hip_runtime.h>
#include <math.h>

// Fused ConvTranspose2d(64->64,k4,s2,p1) + MaxPool2x2 + Hardtanh + mean + tanh
// via bf16 MFMA implicit GEMM. Quad/tap decomposition verified exact (round 1).
//
// MFMA 16x16x32 bf16: A lane l: row=l&15, k=(l>>4)*8+j ; B same with col;
//                     C lane l: col=l&15, row=(l>>4)*4+j   [HW-verified m89]
//
// Round-6 change: TAP-MAJOR inner loop. The 16 (quad,tap) instances span only
// 9 distinct (dh,dw) shifts; iterating shifts and keeping all 4 quad
// accumulators live (acc[4][4] = 64 VGPR) cuts A-fragment LDS reads from
// 128 to 72 per wave. (Round-5 analysis: LDS read pipe ~20 us was the floor,
// MFMA only ~8 us.) No fence / no in-kernel finalize (round-4 lesson: 1024x
// agent-scope fences cost ~100 us with every pipe idle).

typedef __attribute__((ext_vector_type(8))) short short8;
typedef __attribute__((ext_vector_type(4))) float f32x4;

#define XS_ROW 66
#define XS_CI 72          // halfwords per (row,iw) slot: 64 ci + 8 pad
#define XS_CI_U32 36

__device__ __forceinline__ unsigned short f2bf(float f) {
    unsigned int u = __builtin_bit_cast(unsigned int, f);
    u += 0x7fffu + ((u >> 16) & 1u);   // round-to-nearest-even
    return (unsigned short)(u >> 16);
}

// ---------------------------------------------------------------------------
// Weight prep (coalesced reads): read w[ci][co][16] as float4, scatter bf16
// into B-fragment layout: hw idx = (((qt*4 + n)*2 + kb2)*64 + lane)*8 + j
//   ci = kb2*32 + (lane>>4)*8 + j, co = n*16 + (lane&15), (kh,kw) = f(qt).
// Also zeroes partial[2048]. 256 blocks x 64 threads = 1 wave on every CU.
// ---------------------------------------------------------------------------
__global__ void wprep_kernel(const float* __restrict__ w,
                             unsigned short* __restrict__ wsB,
                             float* __restrict__ partial)
{
    const int g = blockIdx.x * 64 + threadIdx.x;   // 0..16383
    const int ci  = g >> 8;
    const int co  = (g >> 2) & 63;
    const int kkq = g & 3;

    const float4 v = *(const float4*)(w + (size_t)ci * 1024 + (size_t)co * 16 + kkq * 4);
    const float vv[4] = {v.x, v.y, v.z, v.w};

    const int n    = co >> 4;
    const int kb2  = ci >> 5;
    const int lane = ((ci >> 3) & 3) * 16 + (co & 15);
    const int j    = ci & 7;

    // inverse of the forward (q,t)->(kh,kw) map
    constexpr int H2Q[4] = {1, 0, 1, 0};
    constexpr int H2T[4] = {1, 0, 0, 1};

    #pragma unroll
    for (int j4 = 0; j4 < 4; ++j4) {
        const int kk = kkq * 4 + j4;
        const int kh = kk >> 2, kw = kk & 3;
        const int q  = H2Q[kh] * 2 + H2Q[kw];
        const int t  = H2T[kh] * 2 + H2T[kw];
        const int qt = q * 4 + t;
        const size_t idx = ((((size_t)(qt * 4 + n)) * 2 + kb2) * 64 + lane) * 8 + j;
        wsB[idx] = f2bf(vv[j4]);
    }
    if (g < 2048) partial[g] = 0.f;
}

// ---------------------------------------------------------------------------
// Main kernel: 1024 blocks x 512 threads (8 waves).
// Block = (batch b, pooled-row-pair rp), XCD-contiguous block map.
// Wave wv: r = wv>>2 (pooled row ph0+r), ch = wv&3 (16-co quarter).
// Per wave: m = 4 px tiles (full 64-px row) x 1 co tile of 16, tap-major.
// ---------------------------------------------------------------------------
__global__ __launch_bounds__(512, 2) void convt_mfma_kernel(
    const float* __restrict__ x,           // [32][64][64][64]
    const float* __restrict__ bias,        // [64]
    const unsigned short* __restrict__ wsB,
    float* __restrict__ partial)           // [2048]
{
    __shared__ __align__(16) unsigned int xs[4 * XS_ROW * XS_CI_U32];  // 38016 B

    const int wg  = blockIdx.x;       // 0..1023
    const int xcd = wg & 7;
    const int k   = wg >> 3;          // 0..127
    const int b   = xcd * 4 + (k >> 5);
    const int rp  = k & 31;
    const int ph0 = rp * 2;
    const int tid = threadIdx.x;

    // ---- stage x tile: input rows ph0-1..ph0+2, iw -1..64, 64 ci (bf16) ----
    {
        const int iw   = tid & 63;
        const int part = tid >> 6;    // 0..7 : ci block of 8
        #pragma unroll
        for (int r4 = 0; r4 < 4; ++r4) {
            const int  ih    = ph0 - 1 + r4;
            const bool rowok = ((unsigned)ih < 64u);
            unsigned int pk[4];
            #pragma unroll
            for (int h = 0; h < 4; ++h) {
                const int ci = part * 8 + h * 2;
                float v0 = 0.f, v1 = 0.f;
                if (rowok) {
                    const size_t base = (((size_t)(b * 64 + ci)) * 64 + ih) * 64 + iw;
                    v0 = x[base];
                    v1 = x[base + 4096];
                }
                pk[h] = (unsigned)f2bf(v0) | ((unsigned)f2bf(v1) << 16);
            }
            unsigned int* dst = &xs[(r4 * XS_ROW + iw + 1) * XS_CI_U32 + part * 4];
            *(uint4*)(dst) = make_uint4(pk[0], pk[1], pk[2], pk[3]);
            if (iw == 0 || iw == 63) {
                const int slot = (iw == 0) ? 0 : 65;
                unsigned int* zp = &xs[(r4 * XS_ROW + slot) * XS_CI_U32 + part * 4];
                *(uint4*)(zp) = make_uint4(0u, 0u, 0u, 0u);
            }
        }
    }
    __syncthreads();

    const int wv   = tid >> 6;        // 0..7
    const int r    = wv >> 2;         // pooled row within pair
    const int ch   = wv & 3;          // co quarter (16 co)
    const int lane = tid & 63;
    const int p    = lane & 15;
    const int hi   = lane >> 4;

    const unsigned short* xs16 = (const unsigned short*)xs;
    const int abase = ((r + 1) * XS_ROW + (p + 1)) * XS_CI + hi * 8;
    const unsigned short* wB = wsB + (size_t)lane * 8;

    // 9 distinct taps; quad q uses tap (dh,dw) iff rows_ok && cols_ok:
    //   dh: -1 -> q<2, 0 -> all, 1 -> q>=2 ; dw: -1 -> q even, 0 -> all, 1 -> q odd
    // t within q: t = 2*(dh!=0) + (dw!=0); qt = q*4+t.
    constexpr int TDH[9] = {-1,-1,-1,  0, 0, 0,  1, 1, 1};
    constexpr int TDW[9] = {-1, 0, 1, -1, 0, 1, -1, 0, 1};

    f32x4 acc[4][4];   // [m][q]
    #pragma unroll
    for (int m = 0; m < 4; ++m)
        #pragma unroll
        for (int q = 0; q < 4; ++q)
            acc[m][q] = (f32x4){0.f, 0.f, 0.f, 0.f};

    #pragma unroll
    for (int tp = 0; tp < 9; ++tp) {
        const int dh = TDH[tp], dw = TDW[tp];
        const int t  = 2 * (dh != 0) + (dw != 0);
        #pragma unroll
        for (int kb2 = 0; kb2 < 2; ++kb2) {
            short8 Af[4];
            const int ao = abase + dh * (XS_ROW * XS_CI) + dw * XS_CI + kb2 * 32;
            #pragma unroll
            for (int m = 0; m < 4; ++m)
                Af[m] = *(const short8*)(xs16 + ao + m * (16 * XS_CI));

            #pragma unroll
            for (int q = 0; q < 4; ++q) {
                const bool rows_ok = (dh == 0) || (dh == -1 ? (q < 2) : (q >= 2));
                const bool cols_ok = (dw == 0) || (dw == -1 ? ((q & 1) == 0)
                                                            : ((q & 1) == 1));
                if (rows_ok && cols_ok) {
                    const int qt = q * 4 + t;
                    const short8 Bf = *(const short8*)(
                        wB + (((size_t)(qt * 4 + ch) * 2 + kb2) << 9));
                    #pragma unroll
                    for (int m = 0; m < 4; ++m)
                        acc[m][q] = __builtin_amdgcn_mfma_f32_16x16x32_bf16(
                            Af[m], Bf, acc[m][q], 0, 0, 0);
                }
            }
        }
    }

    // ---- epilogue: max over quads + bias + hardtanh + sum over 64 px ----
    {
        const int co = ch * 16 + p;
        const float bv = bias[co];
        float s = 0.f;
        #pragma unroll
        for (int m = 0; m < 4; ++m)
            #pragma unroll
            for (int j = 0; j < 4; ++j) {
                const float vm = fmaxf(fmaxf(acc[m][0][j], acc[m][1][j]),
                                       fmaxf(acc[m][2][j], acc[m][3][j]));
                float v = vm + bv;
                v = fminf(fmaxf(v, -1.f), 1.f);
                s += v;
            }
        s += __shfl_xor(s, 16, 64);
        s += __shfl_xor(s, 32, 64);
        if (hi == 0) atomicAdd(&partial[b * 64 + co], s);
    }
}

__global__ void finalize_kernel(const float* __restrict__ partial, float* __restrict__ out)
{
    const int i = blockIdx.x * blockDim.x + threadIdx.x;
    if (i < 2048) out[i] = tanhf(partial[i] * (1.0f / 4096.0f));
}

extern "C" void kernel_launch(void* const* d_in, const int* in_sizes, int n_in,
                              void* d_out, int out_size, void* d_ws, size_t ws_size,
                              hipStream_t stream)
{
    (void)in_sizes; (void)n_in; (void)out_size; (void)ws_size;
    const float* x  = (const float*)d_in[0];
    const float* w  = (const float*)d_in[1];
    const float* bi = (const float*)d_in[2];
    float* out = (float*)d_out;

    unsigned short* wsB     = (unsigned short*)d_ws;           // 131072 B
    float*          partial = (float*)((char*)d_ws + 131072);  // 8192 B

    wprep_kernel<<<256, 64, 0, stream>>>(w, wsB, partial);
    convt_mfma_kernel<<<1024, 512, 0, stream>>>(x, bi, wsB, partial);
    finalize_kernel<<<8, 256, 0, stream>>>(partial, out);
}

// Round 7
// 94.633 us; speedup vs baseline: 2.5457x; 1.0401x over previous
//
#include <hip/hip_runtime.h>
#include <math.h>

// Fused ConvTranspose2d(64->64,k4,s2,p1) + MaxPool2x2 + Hardtanh + mean + tanh
// via bf16 MFMA implicit GEMM. Quad/tap decomposition verified exact (round 1).
//
// MFMA 16x16x32 bf16: A lane l: row=l&15, k=(l>>4)*8+j ; B same with col;
//                     C lane l: col=l&15, row=(l>>4)*4+j   [HW-verified m89]
//
// Round-7 change: 4 pooled rows per block (512 blocks = exactly 2 resident
// per CU -> single scheduling round, no tail). 6-input-row LDS tile (57 KB)
// shared by both row-pairs: staging 6 rows per 4 pooled rows (was 8). Compute
// is the round-6 tap-major loop run twice per wave (sequential pooled rows,
// acc[4][4] = 64 VGPR reused -> no spill).
// History: R4 lesson = no per-block agent-scope fences (~100us stall);
// R3/R4 lesson = keep live accumulator state <= 64 VGPR under (512,2).

typedef __attribute__((ext_vector_type(8))) short short8;
typedef __attribute__((ext_vector_type(4))) float f32x4;

#define XS_ROW 66
#define XS_CI 72          // halfwords per (row,iw) slot: 64 ci + 8 pad
#define XS_CI_U32 36

__device__ __forceinline__ unsigned short f2bf(float f) {
    unsigned int u = __builtin_bit_cast(unsigned int, f);
    u += 0x7fffu + ((u >> 16) & 1u);   // round-to-nearest-even
    return (unsigned short)(u >> 16);
}

// ---------------------------------------------------------------------------
// Weight prep (coalesced reads): read w[ci][co][16] as float4, scatter bf16
// into B-fragment layout: hw idx = (((qt*4 + n)*2 + kb2)*64 + lane)*8 + j
//   ci = kb2*32 + (lane>>4)*8 + j, co = n*16 + (lane&15), (kh,kw) = f(qt).
// Also zeroes partial[2048]. 256 blocks x 64 threads = 1 wave on every CU.
// ---------------------------------------------------------------------------
__global__ void wprep_kernel(const float* __restrict__ w,
                             unsigned short* __restrict__ wsB,
                             float* __restrict__ partial)
{
    const int g = blockIdx.x * 64 + threadIdx.x;   // 0..16383
    const int ci  = g >> 8;
    const int co  = (g >> 2) & 63;
    const int kkq = g & 3;

    const float4 v = *(const float4*)(w + (size_t)ci * 1024 + (size_t)co * 16 + kkq * 4);
    const float vv[4] = {v.x, v.y, v.z, v.w};

    const int n    = co >> 4;
    const int kb2  = ci >> 5;
    const int lane = ((ci >> 3) & 3) * 16 + (co & 15);
    const int j    = ci & 7;

    // inverse of the forward (q,t)->(kh,kw) map
    constexpr int H2Q[4] = {1, 0, 1, 0};
    constexpr int H2T[4] = {1, 0, 0, 1};

    #pragma unroll
    for (int j4 = 0; j4 < 4; ++j4) {
        const int kk = kkq * 4 + j4;
        const int kh = kk >> 2, kw = kk & 3;
        const int q  = H2Q[kh] * 2 + H2Q[kw];
        const int t  = H2T[kh] * 2 + H2T[kw];
        const int qt = q * 4 + t;
        const size_t idx = ((((size_t)(qt * 4 + n)) * 2 + kb2) * 64 + lane) * 8 + j;
        wsB[idx] = f2bf(vv[j4]);
    }
    if (g < 2048) partial[g] = 0.f;
}

// ---------------------------------------------------------------------------
// Main kernel: 512 blocks x 512 threads (8 waves), 2 blocks/CU resident.
// Block = (batch b, pooled-row-quad rp4): pooled rows 4*rp4 .. 4*rp4+3.
// LDS tile: input rows 4*rp4-1 .. 4*rp4+4 (6 rows), iw -1..64, 64 ci bf16.
// Wave wv: rr = wv>>2 -> pooled rows {2rr, 2rr+1} (sequential), ch = wv&3
// (16-co quarter). Per row: tap-major, m = 4 px tiles x 1 co tile.
// ---------------------------------------------------------------------------
__global__ __launch_bounds__(512, 2) void convt_mfma_kernel(
    const float* __restrict__ x,           // [32][64][64][64]
    const float* __restrict__ bias,        // [64]
    const unsigned short* __restrict__ wsB,
    float* __restrict__ partial)           // [2048]
{
    __shared__ __align__(16) unsigned int xs[6 * XS_ROW * XS_CI_U32];  // 57024 B

    const int wg  = blockIdx.x;       // 0..511
    const int xcd = wg & 7;
    const int k   = wg >> 3;          // 0..63
    const int b   = xcd * 4 + (k >> 4);
    const int rp4 = k & 15;
    const int ph0 = rp4 * 4;          // first pooled row of this block
    const int tid = threadIdx.x;

    // ---- stage x tile: input rows ph0-1 .. ph0+4, iw -1..64, 64 ci ----
    {
        const int iw   = tid & 63;
        const int part = tid >> 6;    // 0..7 : ci block of 8
        #pragma unroll
        for (int r6 = 0; r6 < 6; ++r6) {
            const int  ih    = ph0 - 1 + r6;
            const bool rowok = ((unsigned)ih < 64u);
            unsigned int pk[4];
            #pragma unroll
            for (int h = 0; h < 4; ++h) {
                const int ci = part * 8 + h * 2;
                float v0 = 0.f, v1 = 0.f;
                if (rowok) {
                    const size_t base = (((size_t)(b * 64 + ci)) * 64 + ih) * 64 + iw;
                    v0 = x[base];
                    v1 = x[base + 4096];
                }
                pk[h] = (unsigned)f2bf(v0) | ((unsigned)f2bf(v1) << 16);
            }
            unsigned int* dst = &xs[(r6 * XS_ROW + iw + 1) * XS_CI_U32 + part * 4];
            *(uint4*)(dst) = make_uint4(pk[0], pk[1], pk[2], pk[3]);
            if (iw == 0 || iw == 63) {
                const int slot = (iw == 0) ? 0 : 65;
                unsigned int* zp = &xs[(r6 * XS_ROW + slot) * XS_CI_U32 + part * 4];
                *(uint4*)(zp) = make_uint4(0u, 0u, 0u, 0u);
            }
        }
    }
    __syncthreads();

    const int wv   = tid >> 6;        // 0..7
    const int rr   = wv >> 2;         // row-pair within block
    const int ch   = wv & 3;          // co quarter (16 co)
    const int lane = tid & 63;
    const int p    = lane & 15;
    const int hi   = lane >> 4;

    const unsigned short* xs16 = (const unsigned short*)xs;
    const unsigned short* wB = wsB + (size_t)lane * 8;

    // 9 distinct taps; quad q uses tap (dh,dw) iff rows_ok && cols_ok:
    //   dh: -1 -> q<2, 0 -> all, 1 -> q>=2 ; dw: -1 -> q even, 0 -> all, 1 -> q odd
    // t within q: t = 2*(dh!=0) + (dw!=0); qt = q*4+t.
    constexpr int TDH[9] = {-1,-1,-1,  0, 0, 0,  1, 1, 1};
    constexpr int TDW[9] = {-1, 0, 1, -1, 0, 1, -1, 0, 1};

    const int   co = ch * 16 + p;
    const float bv = bias[co];
    float s = 0.f;

    #pragma unroll
    for (int pr = 0; pr < 2; ++pr) {
        const int prow  = rr * 2 + pr;   // block-relative pooled row 0..3
        const int abase = ((prow + 1) * XS_ROW + (p + 1)) * XS_CI + hi * 8;

        f32x4 acc[4][4];   // [m][q]
        #pragma unroll
        for (int m = 0; m < 4; ++m)
            #pragma unroll
            for (int q = 0; q < 4; ++q)
                acc[m][q] = (f32x4){0.f, 0.f, 0.f, 0.f};

        #pragma unroll
        for (int tp = 0; tp < 9; ++tp) {
            const int dh = TDH[tp], dw = TDW[tp];
            const int t  = 2 * (dh != 0) + (dw != 0);
            #pragma unroll
            for (int kb2 = 0; kb2 < 2; ++kb2) {
                short8 Af[4];
                const int ao = abase + dh * (XS_ROW * XS_CI) + dw * XS_CI + kb2 * 32;
                #pragma unroll
                for (int m = 0; m < 4; ++m)
                    Af[m] = *(const short8*)(xs16 + ao + m * (16 * XS_CI));

                #pragma unroll
                for (int q = 0; q < 4; ++q) {
                    const bool rows_ok = (dh == 0) || (dh == -1 ? (q < 2) : (q >= 2));
                    const bool cols_ok = (dw == 0) || (dw == -1 ? ((q & 1) == 0)
                                                                : ((q & 1) == 1));
                    if (rows_ok && cols_ok) {
                        const int qt = q * 4 + t;
                        const short8 Bf = *(const short8*)(
                            wB + (((size_t)(qt * 4 + ch) * 2 + kb2) << 9));
                        #pragma unroll
                        for (int m = 0; m < 4; ++m)
                            acc[m][q] = __builtin_amdgcn_mfma_f32_16x16x32_bf16(
                                Af[m], Bf, acc[m][q], 0, 0, 0);
                    }
                }
            }
        }

        // max over quads + bias + hardtanh + accumulate this row's 64 px
        #pragma unroll
        for (int m = 0; m < 4; ++m)
            #pragma unroll
            for (int j = 0; j < 4; ++j) {
                const float vm = fmaxf(fmaxf(acc[m][0][j], acc[m][1][j]),
                                       fmaxf(acc[m][2][j], acc[m][3][j]));
                float v = vm + bv;
                v = fminf(fmaxf(v, -1.f), 1.f);
                s += v;
            }
    }

    s += __shfl_xor(s, 16, 64);
    s += __shfl_xor(s, 32, 64);
    if (hi == 0) atomicAdd(&partial[b * 64 + co], s);
}

__global__ void finalize_kernel(const float* __restrict__ partial, float* __restrict__ out)
{
    const int i = blockIdx.x * blockDim.x + threadIdx.x;
    if (i < 2048) out[i] = tanhf(partial[i] * (1.0f / 4096.0f));
}

extern "C" void kernel_launch(void* const* d_in, const int* in_sizes, int n_in,
                              void* d_out, int out_size, void* d_ws, size_t ws_size,
                              hipStream_t stream)
{
    (void)in_sizes; (void)n_in; (void)out_size; (void)ws_size;
    const float* x  = (const float*)d_in[0];
    const float* w  = (const float*)d_in[1];
    const float* bi = (const float*)d_in[2];
    float* out = (float*)d_out;

    unsigned short* wsB     = (unsigned short*)d_ws;           // 131072 B
    float*          partial = (float*)((char*)d_ws + 131072);  // 8192 B

    wprep_kernel<<<256, 64, 0, stream>>>(w, wsB, partial);
    convt_mfma_kernel<<<512, 512, 0, stream>>>(x, bi, wsB, partial);
    finalize_kernel<<<8, 256, 0, stream>>>(partial, out);
}